// Round 12
// baseline (56.352 us; speedup 1.0000x reference)
//
#include <hip/hip_runtime.h>
#include <hip/hip_bf16.h>

// N=4, L=128, S=64, D=256, H=8. Heads collapse; weights pre-compose:
//   Mqk = Wq Wk^T, Mvo = Wv WoSum (WoSum = sum_h Wo_h)
// Per slice sl=n*64+s: T = Xq@Mqk; S = T@Xk^T; P = softmax(S/16+mask);
// B1 = Xv@Mvo; out = P@B1 + bo.  One block (512 thr / 8 waves)/slice.
// All GEMMs mfma_f32_32x32x16_bf16. Frags: lane l -> row l&31, k=(l>>5)*8+j.
// D: col=lane&31, row(reg)=(r&3)+8*(r>>2)+4*(l>>5)  [HW-verified].
// Round 12 (r11 + three changes):
//  - fills issued deeper: Xk at kernel start, Xv in phase3 (hides L3/HBM BW)
//  - A-stage swizzle widened to (row&15)<<4: 4-way -> 2-way (free) on xfrag
//  - Timg written as b128 frags via mkfrag (same verified reshape as Pimg)
// LDS: A [0,64K) staged X (Xq->Xk->Xv); Timg [64K,128K) [rt4][ks16][64][16]
//      (dead after af hoist) -> Pimg [64K,96K) ; scr [96K,+2K).

using bf16x4 = __attribute__((ext_vector_type(4))) __bf16;
using bf16x8 = __attribute__((ext_vector_type(8))) __bf16;
using f32x16 = __attribute__((ext_vector_type(16))) float;

#define MFMA32(a, b, c) __builtin_amdgcn_mfma_f32_32x32x16_bf16((a), (b), (c), 0, 0, 0)

__device__ __forceinline__ bf16x8 cvt8(float4 f0, float4 f1) {
  bf16x8 a;
  a[0]=(__bf16)f0.x; a[1]=(__bf16)f0.y; a[2]=(__bf16)f0.z; a[3]=(__bf16)f0.w;
  a[4]=(__bf16)f1.x; a[5]=(__bf16)f1.y; a[6]=(__bf16)f1.z; a[7]=(__bf16)f1.w;
  return a;
}
__device__ __forceinline__ f32x16 zero16() {
  f32x16 z;
#pragma unroll
  for (int j = 0; j < 16; ++j) z[j] = 0.f;
  return z;
}
__device__ __forceinline__ unsigned pk(float a, float b) {
  union { __bf16 h[2]; unsigned u; } x;
  x.h[0] = (__bf16)a; x.h[1] = (__bf16)b;
  return x.u;
}
__device__ __forceinline__ bf16x8 u4frag(uint4 w) {
  union { uint4 u; bf16x8 f; } x;
  x.u = w;
  return x.f;
}
// D-regs (8 consecutive, base 8*s16) of a 32-wide tile -> one A/B frag chunk.
// Lane axis preserved; reg axis -> k-chunk elements. Verified (r11 Pimg/B1).
__device__ __forceinline__ uint4 mkfrag(const float* a8, int hl) {
  unsigned p00 = pk(a8[0], a8[1]), p01 = pk(a8[2], a8[3]);
  unsigned p10 = pk(a8[4], a8[5]), p11 = pk(a8[6], a8[7]);
  unsigned r0 = __shfl_xor((int)(hl ? p00 : p10), 32);
  unsigned r1 = __shfl_xor((int)(hl ? p01 : p11), 32);
  uint4 w;
  w.x = hl ? r0 : p00;  w.y = hl ? r1 : p01;
  w.z = hl ? p10 : r0;  w.w = hl ? p11 : r1;
  return w;
}

// ---------------------------------------------------------------- prep
__global__ __launch_bounds__(512) void prep_pack(
    const float* __restrict__ Wq, const float* __restrict__ Wk,
    const float* __restrict__ Wv, const float* __restrict__ Wo,
    const int* __restrict__ mask,
    __bf16* __restrict__ mqk, __bf16* __restrict__ mvo,
    unsigned* __restrict__ mbits) {
  __shared__ float wt[256 * 33];
  const int t = threadIdx.x, lane = t & 63, w = t >> 6;
  const int lq = lane & 31, hl = lane >> 5;
  const int ct = blockIdx.x;
  const bool isV = blockIdx.y != 0;
  if (!isV) {
    int gid = ct * 512 + t;
    if (gid < 2048) {
      const int* mrow = mask + gid * 32;
      unsigned mw = 0;
#pragma unroll
      for (int b = 0; b < 32; ++b) mw |= (mrow[b] != 0 ? 1u : 0u) << b;
      mbits[gid] = mw;
    }
  } else {
#pragma unroll
    for (int i = 0; i < 16; ++i) {
      int cell = i * 512 + t;
      int e2 = cell >> 5, eol = cell & 31;
      float ssum = 0.f;
#pragma unroll
      for (int h = 0; h < 8; ++h)
        ssum += Wo[((size_t)(h * 256 + e2)) * 256 + ct * 32 + eol];
      wt[e2 * 33 + eol] = ssum;
    }
    __syncthreads();
  }
  const float* Aw = isV ? Wv : Wq;
  bf16x8 afr[16], bfr[16];
#pragma unroll
  for (int ks = 0; ks < 16; ++ks) {
    const float* p = Aw + (size_t)(w * 32 + lq) * 256 + ks * 16 + hl * 8;
    afr[ks] = cvt8(*(const float4*)p, *(const float4*)(p + 4));
  }
  if (!isV) {
#pragma unroll
    for (int ks = 0; ks < 16; ++ks) {
      const float* p = Wk + (size_t)(ct * 32 + lq) * 256 + ks * 16 + hl * 8;
      bfr[ks] = cvt8(*(const float4*)p, *(const float4*)(p + 4));
    }
  } else {
#pragma unroll
    for (int ks = 0; ks < 16; ++ks)
#pragma unroll
      for (int jj = 0; jj < 8; ++jj)
        bfr[ks][jj] = (__bf16)wt[(ks * 16 + hl * 8 + jj) * 33 + lq];
  }
  f32x16 acc = zero16();
#pragma unroll
  for (int ks = 0; ks < 16; ++ks) acc = MFMA32(afr[ks], bfr[ks], acc);
  char* dstb = (char*)(isV ? mvo : mqk);
#pragma unroll
  for (int a = 0; a < 4; ++a) {
    bf16x4 v;
#pragma unroll
    for (int j = 0; j < 4; ++j) v[j] = (__bf16)acc[4 * a + j];
    *(bf16x4*)(dstb + ct * 16384 + (2 * w + (a >> 1)) * 1024 +
               (lq + 32 * (a & 1)) * 16 + hl * 8) = v;
  }
}

// ---------------------------------------------------------------- fused
__global__ __launch_bounds__(512) void fused_attn(
    const float* __restrict__ Xv, const float* __restrict__ Xk,
    const float* __restrict__ Xq, const unsigned* __restrict__ mbits,
    const __bf16* __restrict__ mqk, const __bf16* __restrict__ mvo,
    const float* __restrict__ bo, float* __restrict__ out) {
  extern __shared__ char lds[];
  char* A     = lds;                 // 64KB staged X
  char* Timg  = lds + 65536;         // 64KB [rt][ks][64][16] (dead after hoist)
  char* Pimg  = lds + 65536;         // 32KB (reuses Timg low)
  float* scr  = (float*)(lds + 98304);  // 2KB (Timg high, dead post-b3)
  const int t = threadIdx.x, lane = t & 63, w = t >> 6;
  const int lq = lane & 31, hl = lane >> 5;
  const int qt = w & 3, kh = w >> 2;
  const int sl = blockIdx.x, n = sl >> 6, s = sl & 63;

  auto fill = [&](const float* __restrict__ X, float4* vr) {
#pragma unroll
    for (int i = 0; i < 8; ++i) {
      int f8 = i * 512 + t, row = f8 >> 5, c8 = f8 & 31;
      const float* src = X + ((size_t)(n * 8192 + row * 64 + s)) * 256 + c8 * 8;
      vr[2 * i]     = *reinterpret_cast<const float4*>(src);
      vr[2 * i + 1] = *reinterpret_cast<const float4*>(src + 4);
    }
  };
  auto flushv = [&](const float4* vr) {
#pragma unroll
    for (int i = 0; i < 8; ++i) {
      int f8 = i * 512 + t, row = f8 >> 5, c8 = f8 & 31;
      bf16x8 b;
      b[0]=(__bf16)vr[2*i].x;   b[1]=(__bf16)vr[2*i].y;
      b[2]=(__bf16)vr[2*i].z;   b[3]=(__bf16)vr[2*i].w;
      b[4]=(__bf16)vr[2*i+1].x; b[5]=(__bf16)vr[2*i+1].y;
      b[6]=(__bf16)vr[2*i+1].z; b[7]=(__bf16)vr[2*i+1].w;
      *reinterpret_cast<bf16x8*>(A + row * 512 + ((c8 * 16) ^ ((row & 15) << 4))) = b;
    }
  };
  auto xfrag = [&](int brow, int ks) -> bf16x8 {
    return *reinterpret_cast<const bf16x8*>(
        A + brow * 512 + ((ks * 32 + hl * 16) ^ ((brow & 15) << 4)));
  };

  // prologue: Mqk tile loads + BOTH Xq and Xk fills issued up-front
  bf16x8 wf[16];
  {
    const bf16x8* wp = reinterpret_cast<const bf16x8*>(mqk);
#pragma unroll
    for (int ks = 0; ks < 16; ++ks) wf[ks] = wp[(w * 16 + ks) * 64 + lane];
  }
  float4 vrp[16];
  {
    float4 vr[16];
    fill(Xq, vr);
    fill(Xk, vrp);                               // deep prefetch (cover: ph1+ph2)
    flushv(vr);
  }
  __syncthreads();                               // b1

  // ---- phase 2: T = Xq@Mqk (wave w = dout-tile); D lanes=q, regs=dout
#pragma unroll
  for (int rt = 0; rt < 4; ++rt) {
    f32x16 acc = zero16();
#pragma unroll
    for (int ks = 0; ks < 16; ++ks)
      acc = MFMA32(wf[ks], xfrag(rt * 32 + lq, ks), acc);
#pragma unroll
    for (int s16 = 0; s16 < 2; ++s16) {
      float a8[8];
#pragma unroll
      for (int i = 0; i < 8; ++i) a8[i] = acc[8 * s16 + i];
      uint4 wd = mkfrag(a8, hl);
      *(uint4*)(Timg + rt * 16384 + (2 * w + s16) * 1024 + lane * 16) = wd;
    }
  }
  __syncthreads();                               // b2

  // ---- phase 3: hoist T B-frags (lane->q) for qt; stage Xk; prefetch Xv
  bf16x8 af[16];
#pragma unroll
  for (int ks = 0; ks < 16; ++ks)
    af[ks] = *reinterpret_cast<const bf16x8*>(Timg + qt * 16384 + ks * 1024 + lane * 16);
  flushv(vrp);
  fill(Xv, vrp);                                 // prefetch (cover: b3+S+softmax)
  __syncthreads();                               // b3

  // ---- phase 4: S = Xk x T (swapped: lane->q, regs->k2)
  unsigned mw0 = mbits[((size_t)n * 128 + qt * 32 + lq) * 4 + 2 * kh];
  unsigned mw1 = mbits[((size_t)n * 128 + qt * 32 + lq) * 4 + 2 * kh + 1];
  f32x16 acc[2];
#pragma unroll
  for (int c = 0; c < 2; ++c) {
    acc[c] = zero16();
    int kt = 2 * kh + c;
#pragma unroll
    for (int ks = 0; ks < 16; ++ks)
      acc[c] = MFMA32(xfrag(kt * 32 + lq, ks), af[ks], acc[c]);
  }
  float mx = -3e38f;
#pragma unroll
  for (int c = 0; c < 2; ++c) {
    unsigned mw = c ? mw1 : mw0;
#pragma unroll
    for (int r = 0; r < 16; ++r) {
      int bit = (r & 3) + 8 * (r >> 2) + 4 * hl;
      float sv = ((mw >> bit) & 1u) ? acc[c][r] * 0.0625f : -6.25e18f;  // -1e20/16
      acc[c][r] = sv;
      mx = fmaxf(mx, sv);
    }
  }
  mx = fmaxf(mx, __shfl_xor(mx, 32));
  float sum = 0.f;
#pragma unroll
  for (int c = 0; c < 2; ++c)
#pragma unroll
    for (int r = 0; r < 16; ++r) {
      float e = __expf(acc[c][r] - mx);
      acc[c][r] = e;
      sum += e;
    }
  sum += __shfl_xor(sum, 32);
  if (lane < 32) {
    float2* s2 = reinterpret_cast<float2*>(scr);
    s2[(qt * 2 + kh) * 32 + lane] = make_float2(mx, sum);
  }
  __syncthreads();                               // b4

  // ---- phase 5: pair-combine; Pimg b128 writes; issue vf; stage Xv
  {
    float2 pr = reinterpret_cast<const float2*>(scr)[(qt * 2 + (kh ^ 1)) * 32 + lq];
    float M = fmaxf(mx, pr.x);
    float tot = sum * __expf(mx - M) + pr.y * __expf(pr.x - M);
    float scale = __expf(mx - M) / tot;
#pragma unroll
    for (int c = 0; c < 2; ++c)
#pragma unroll
      for (int r = 0; r < 16; ++r) acc[c][r] *= scale;
  }
  bf16x8 vf[16];
  {
    const bf16x8* vp = reinterpret_cast<const bf16x8*>(mvo);
#pragma unroll
    for (int ks = 0; ks < 16; ++ks) vf[ks] = vp[(w * 16 + ks) * 64 + lane];
  }
#pragma unroll
  for (int c = 0; c < 2; ++c) {
    int kt = 2 * kh + c;
#pragma unroll
    for (int s16 = 0; s16 < 2; ++s16) {
      float a8[8];
#pragma unroll
      for (int i = 0; i < 8; ++i) a8[i] = acc[c][8 * s16 + i];
      uint4 wd = mkfrag(a8, hl);
      *(uint4*)(Pimg + qt * 8192 + (kt * 2 + s16) * 1024 + lane * 16) = wd;
    }
  }
  flushv(vrp);                                   // Xv -> A
  __syncthreads();                               // b5

  // ---- phase 6: B1 = Xv x Mvo (wave w = e-tile), reshape to out A-frags
  bf16x8 afB1[8];
#pragma unroll
  for (int rt = 0; rt < 4; ++rt) {
    f32x16 a1 = zero16();
#pragma unroll
    for (int ks = 0; ks < 16; ++ks)
      a1 = MFMA32(xfrag(rt * 32 + lq, ks), vf[ks], a1);
#pragma unroll
    for (int s16 = 0; s16 < 2; ++s16) {
      float a8[8];
#pragma unroll
      for (int i = 0; i < 8; ++i) a8[i] = a1[8 * s16 + i];
      afB1[rt * 2 + s16] = u4frag(mkfrag(a8, hl));
    }
  }

  // ---- phase 7: out = B1^T x P + bo (wave w = e-tile, loop q-tiles)
#pragma unroll
  for (int q4 = 0; q4 < 4; ++q4) {
    f32x16 a2 = zero16();
#pragma unroll
    for (int ks = 0; ks < 8; ++ks) {
      bf16x8 pfr = *reinterpret_cast<const bf16x8*>(
          Pimg + q4 * 8192 + ks * 1024 + lane * 16);
      a2 = MFMA32(afB1[ks], pfr, a2);
    }
    float* orow = out + ((size_t)(n * 8192) + (q4 * 32 + lq) * 64 + s) * 256;
#pragma unroll
    for (int a = 0; a < 4; ++a) {
      float4 bv = *reinterpret_cast<const float4*>(bo + w * 32 + 8 * a + 4 * hl);
      float4 st;
      st.x = a2[4*a]   + bv.x; st.y = a2[4*a+1] + bv.y;
      st.z = a2[4*a+2] + bv.z; st.w = a2[4*a+3] + bv.w;
      *reinterpret_cast<float4*>(orow + w * 32 + 8 * a + 4 * hl) = st;
    }
  }
}

extern "C" void kernel_launch(void* const* d_in, const int* in_sizes, int n_in,
                              void* d_out, int out_size, void* d_ws, size_t ws_size,
                              hipStream_t stream) {
  const float* values = (const float*)d_in[0];
  const float* keys   = (const float*)d_in[1];
  const float* query  = (const float*)d_in[2];
  const int*   mask   = (const int*)d_in[3];
  const float* Wq     = (const float*)d_in[4];
  const float* Wk     = (const float*)d_in[5];
  const float* Wv     = (const float*)d_in[6];
  const float* Wo     = (const float*)d_in[7];
  const float* bo     = (const float*)d_in[8];
  float* out = (float*)d_out;

  char* w = (char*)d_ws;
  __bf16*   mqk   = (__bf16*)w;   w += 131072;   // pack [8 ct32][16 ks][64][8]
  __bf16*   mvo   = (__bf16*)w;   w += 131072;
  unsigned* mbits = (unsigned*)w; w += 8192;     // [n][q][4] k-bitwords

  prep_pack<<<dim3(8, 2), 512, 0, stream>>>(Wq, Wk, Wv, Wo, mask, mqk, mvo, mbits);
  fused_attn<<<256, 512, 131072, stream>>>(values, keys, query, mbits,
                                           mqk, mvo, bo, out);
}